// Round 1
// baseline (643.776 us; speedup 1.0000x reference)
//
#include <hip/hip_runtime.h>
#include <math.h>

// Gating kernel: logits = x @ W^T + b; softmax over E=16; top-2 scatter.
// Outputs (concatenated in d_out): gated^T [16,65536], weights^T [16,65536].
//
// Strategy: thread == token. 16 logits accumulate in-lane (no cross-lane
// reduction). x staged through LDS per 64-dim chunk for coalescing; W read
// via wave-uniform indices -> scalar loads (SMEM pipe). Register prefetch
// double-buffers the HBM stream against compute. Memory-bound: ~264 MB
// traffic -> ~42 us floor at 6.3 TB/s.

constexpr int D      = 1024;
constexpr int NE     = 16;
constexpr int TPB    = 64;            // tokens (= threads) per block, 1 wave
constexpr int CHUNK  = 64;            // dims per chunk
constexpr int NCHUNK = D / CHUNK;     // 16
constexpr int STRIDE = CHUNK + 4;     // 68 floats: pad keeps 16B align, breaks pow2 banks
constexpr int NTOK   = 8 * 8192;      // 65536 tokens

__global__ __launch_bounds__(TPB) void gating_kernel(
    const float* __restrict__ x,
    const float* __restrict__ W,
    const float* __restrict__ bias,
    float* __restrict__ out)
{
    __shared__ float lds[TPB * STRIDE];   // 64 * 68 * 4 = 17.4 KB
    const int t = threadIdx.x;
    const long blockTok = (long)blockIdx.x * TPB;
    const float* xb = x + blockTok * D;

    // ---- prefetch chunk 0 into registers (coalesced float4) ----
    float4 pf[16];
    #pragma unroll
    for (int p = 0; p < 16; ++p) {
        const int idx = p * TPB + t;      // 0..1023 element-groups of the chunk
        const int r   = idx >> 4;         // token row 0..63
        const int cg  = idx & 15;         // float4 column 0..15
        pf[p] = *(const float4*)(xb + r * D + cg * 4);
    }

    float acc[NE];
    #pragma unroll
    for (int e = 0; e < NE; ++e) acc[e] = 0.0f;

    for (int c = 0; c < NCHUNK; ++c) {
        if (c) __syncthreads();           // prior chunk's LDS reads done
        // ---- spill prefetch regs into LDS (padded rows) ----
        #pragma unroll
        for (int p = 0; p < 16; ++p) {
            const int idx = p * TPB + t;
            const int r   = idx >> 4;
            const int cg  = idx & 15;
            *(float4*)&lds[r * STRIDE + cg * 4] = pf[p];
        }
        __syncthreads();
        // ---- issue next chunk's global loads (overlap with compute) ----
        if (c + 1 < NCHUNK) {
            #pragma unroll
            for (int p = 0; p < 16; ++p) {
                const int idx = p * TPB + t;
                const int r   = idx >> 4;
                const int cg  = idx & 15;
                pf[p] = *(const float4*)(xb + r * D + (c + 1) * CHUNK + cg * 4);
            }
        }
        // ---- compute: this lane's token row vs all 16 experts ----
        #pragma unroll
        for (int d4 = 0; d4 < CHUNK / 4; ++d4) {
            const float4 xv = *(const float4*)&lds[t * STRIDE + d4 * 4];
            #pragma unroll
            for (int e = 0; e < NE; ++e) {
                // wave-uniform index -> scalar load (SMEM pipe)
                const float4 wv = *(const float4*)(W + e * D + c * CHUNK + d4 * 4);
                acc[e] = fmaf(xv.x, wv.x, acc[e]);
                acc[e] = fmaf(xv.y, wv.y, acc[e]);
                acc[e] = fmaf(xv.z, wv.z, acc[e]);
                acc[e] = fmaf(xv.w, wv.w, acc[e]);
            }
        }
    }

    // ---- epilogue: softmax over 16 logits, top-2, scatter, store ----
    float logits[NE];
    float m = -INFINITY;
    #pragma unroll
    for (int e = 0; e < NE; ++e) {
        logits[e] = acc[e] + bias[e];
        m = fmaxf(m, logits[e]);
    }
    float w[NE];
    float s = 0.0f;
    #pragma unroll
    for (int e = 0; e < NE; ++e) {
        w[e] = __expf(logits[e] - m);
        s += w[e];
    }
    const float inv = 1.0f / s;
    #pragma unroll
    for (int e = 0; e < NE; ++e) w[e] *= inv;

    // top-2 (ties -> lowest index, matching lax.top_k)
    float b1 = -1.0f; int i1 = 0;
    float b2 = -1.0f; int i2 = 0;
    #pragma unroll
    for (int e = 0; e < NE; ++e) {
        if (w[e] > b1)      { b2 = b1; i2 = i1; b1 = w[e]; i1 = e; }
        else if (w[e] > b2) { b2 = w[e]; i2 = e; }
    }

    float* __restrict__ out0 = out;                     // gated^T [16][65536]
    float* __restrict__ out1 = out + (long)NE * NTOK;   // weights^T [16][65536]
    const long gtok = blockTok + t;
    #pragma unroll
    for (int e = 0; e < NE; ++e) {
        const float g = (e == i1) ? b1 : ((e == i2) ? b2 : 0.0f);
        out0[(long)e * NTOK + gtok] = g;      // coalesced across lanes per e
        out1[(long)e * NTOK + gtok] = w[e];
    }
}

extern "C" void kernel_launch(void* const* d_in, const int* in_sizes, int n_in,
                              void* d_out, int out_size, void* d_ws, size_t ws_size,
                              hipStream_t stream) {
    const float* x = (const float*)d_in[0];
    const float* W = (const float*)d_in[1];
    const float* b = (const float*)d_in[2];
    float* out = (float*)d_out;

    dim3 grid(NTOK / TPB);   // 1024 blocks -> 4 blocks/CU
    dim3 block(TPB);
    gating_kernel<<<grid, block, 0, stream>>>(x, W, b, out);
}